// Round 5
// baseline (7682.252 us; speedup 1.0000x reference)
//
#include <hip/hip_runtime.h>
#include <math.h>
#include <stdio.h>

#define NTOK 65536
#define DMODEL 256
#define DI 512
#define DS 16
#define CHUNK 128
#define NCHUNK (NTOK / CHUNK)   // 512
#define QCH 128                 // channels per scan quarter

__device__ __forceinline__ float sigf(float x) { return 1.0f / (1.0f + expf(-x)); }
__device__ __forceinline__ float clampf(float x) { return fminf(fmaxf(x, -3.0e4f), 3.0e4f); }

// ---------------------------------------------------------------------------
// fused_xmod: per 64-token block computes
//   g       = gelu(LN(guidance @ gg1_w.T + gg1_b))      (recomputed per k-chunk)
//   gate_in = sigmoid(g @ gg2_w[0:512].T + gg2_b)       (K=512 GEMM)
//   x_in    = x @ in_proj_w[0:512].T                    (K=256 GEMM, +4 halo rows)
//   x_mod   = silu(causal_conv(x_in)) * gate_in  -> P1
// ---------------------------------------------------------------------------
__global__ __launch_bounds__(256) void fused_xmod(
    const float* x, const float* in_proj_w, const float* guidance,
    const float* gg1_w, const float* gg1_b, const float* ln_g, const float* ln_b,
    const float* gg2_w, const float* gg2_b,
    const float* conv_w, const float* conv_b, float* x_mod)
{
    __shared__ float guid[64][4];
    __shared__ float mu_s[64], rstd_s[64];
    __shared__ float Tk[16][69];   // g-chunk [16][64] or x-chunk [16][68]
    __shared__ float Wt[16][65];
    __shared__ float xt[68][65];   // x_in tile: rows row0-4 .. row0+63
    const int tid = threadIdx.x;
    const int lane = tid & 63;
    const int wave = tid >> 6;
    const int row0 = blockIdx.x * 64;
    const int tr = (tid >> 4) * 4;
    const int tc = (tid & 15) * 4;
    const int rh = tid >> 6, chh = tid & 63;

    if (tid < 192) guid[tid / 3][tid % 3] = guidance[(size_t)row0 * 3 + tid];
    __syncthreads();

    for (int i = 0; i < 16; i++) {               // each wave: 16 tokens
        int tok = wave * 16 + i;
        float g0 = guid[tok][0], g1 = guid[tok][1], g2 = guid[tok][2];
        float sum = 0.f, sumsq = 0.f;
#pragma unroll
        for (int j = 0; j < 8; j++) {
            int dim = j * 64 + lane;
            float t = gg1_w[dim*3]*g0 + gg1_w[dim*3+1]*g1 + gg1_w[dim*3+2]*g2 + gg1_b[dim];
            sum += t; sumsq += t * t;
        }
#pragma unroll
        for (int off = 32; off >= 1; off >>= 1) {
            sum += __shfl_xor(sum, off); sumsq += __shfl_xor(sumsq, off);
        }
        if (lane == 0) {
            float mu = sum * (1.f / 512.f);
            float var = fmaxf(sumsq * (1.f / 512.f) - mu * mu, 0.f);
            mu_s[tok] = mu;
            rstd_s[tok] = 1.f / sqrtf(var + 1e-5f);
        }
    }
    __syncthreads();

    for (int ct = 0; ct < 8; ct++) {
        // ---- gate GEMM (K=512) ----
        float acc_g[4][4];
#pragma unroll
        for (int i = 0; i < 4; i++)
#pragma unroll
            for (int j = 0; j < 4; j++) acc_g[i][j] = 0.f;
        for (int k0 = 0; k0 < 512; k0 += 16) {
            __syncthreads();
            for (int i = tid; i < 16 * 64; i += 256) {
                int k = i >> 6, tok = i & 63;
                int dim = k0 + k;
                float t = gg1_w[dim*3]*guid[tok][0] + gg1_w[dim*3+1]*guid[tok][1]
                        + gg1_w[dim*3+2]*guid[tok][2] + gg1_b[dim];
                t = (t - mu_s[tok]) * rstd_s[tok] * ln_g[dim] + ln_b[dim];
                Tk[k][tok] = 0.5f * t * (1.f + erff(t * 0.70710678118654752440f));
            }
            for (int i = tid; i < 16 * 64; i += 256) {
                int n = i >> 4, k = i & 15;
                Wt[k][n] = gg2_w[(size_t)(64 * ct + n) * 512 + k0 + k];
            }
            __syncthreads();
            float part[4][4];
#pragma unroll
            for (int i = 0; i < 4; i++)
#pragma unroll
                for (int j = 0; j < 4; j++) part[i][j] = 0.f;
#pragma unroll
            for (int kk = 0; kk < 16; kk++) {
                float a[4], b[4];
#pragma unroll
                for (int i = 0; i < 4; i++) a[i] = Tk[kk][tr + i];
#pragma unroll
                for (int j = 0; j < 4; j++) b[j] = Wt[kk][tc + j];
#pragma unroll
                for (int i = 0; i < 4; i++)
#pragma unroll
                    for (int j = 0; j < 4; j++) part[i][j] += a[i] * b[j];
            }
#pragma unroll
            for (int i = 0; i < 4; i++)
#pragma unroll
                for (int j = 0; j < 4; j++) acc_g[i][j] += part[i][j];
        }
        // ---- x_in GEMM (K=256, 64 main rows + 4 halo rows) ----
        float acc_x[4][4];
#pragma unroll
        for (int i = 0; i < 4; i++)
#pragma unroll
            for (int j = 0; j < 4; j++) acc_x[i][j] = 0.f;
        float acc_h = 0.f;
        for (int k0 = 0; k0 < 256; k0 += 16) {
            __syncthreads();
            for (int i = tid; i < 16 * 68; i += 256) {
                int l = i >> 4, k = i & 15;
                int gr = row0 - 4 + l;
                Tk[k][l] = (gr >= 0) ? x[(size_t)gr * 256 + k0 + k] : 0.f;
            }
            for (int i = tid; i < 16 * 64; i += 256) {
                int n = i >> 4, k = i & 15;
                Wt[k][n] = in_proj_w[(size_t)(64 * ct + n) * 256 + k0 + k];
            }
            __syncthreads();
            float part[4][4];
#pragma unroll
            for (int i = 0; i < 4; i++)
#pragma unroll
                for (int j = 0; j < 4; j++) part[i][j] = 0.f;
            float ph = 0.f;
#pragma unroll
            for (int kk = 0; kk < 16; kk++) {
                float a[4], b[4];
#pragma unroll
                for (int i = 0; i < 4; i++) a[i] = Tk[kk][4 + tr + i];
#pragma unroll
                for (int j = 0; j < 4; j++) b[j] = Wt[kk][tc + j];
#pragma unroll
                for (int i = 0; i < 4; i++)
#pragma unroll
                    for (int j = 0; j < 4; j++) part[i][j] += a[i] * b[j];
                ph += Tk[kk][rh] * Wt[kk][chh];
            }
#pragma unroll
            for (int i = 0; i < 4; i++)
#pragma unroll
                for (int j = 0; j < 4; j++) acc_x[i][j] += part[i][j];
            acc_h += ph;
        }
#pragma unroll
        for (int i = 0; i < 4; i++)
#pragma unroll
            for (int j = 0; j < 4; j++) xt[4 + tr + i][tc + j] = acc_x[i][j];
        xt[rh][chh] = acc_h;   // rows row0-4..row0-1 (0 if gr<0: inputs were 0)
        __syncthreads();
        // ---- epilogue: conv + silu + gate ----
#pragma unroll
        for (int i = 0; i < 4; i++) {
            int r = row0 + tr + i;
#pragma unroll
            for (int j = 0; j < 4; j++) {
                int c = 64 * ct + tc + j;
                float cv = conv_b[c];
#pragma unroll
                for (int k = 0; k < 4; k++)
                    cv += conv_w[c * 4 + k] * xt[tr + i + 1 + k][tc + j];
                float sx = cv * sigf(cv);
                float gate = sigf(acc_g[i][j] + gg2_b[c]);
                x_mod[(size_t)r * 512 + c] = sx * gate;
            }
        }
        __syncthreads();
    }
}

// ---------------------------------------------------------------------------
// fused_wgate: w_gate = silu(z) * sigmoid(g @ gg2_w[1024:1536].T + b) -> P2
//   z = x @ in_proj_w[512:1024].T
// ---------------------------------------------------------------------------
__global__ __launch_bounds__(256) void fused_wgate(
    const float* x, const float* in_proj_w, const float* guidance,
    const float* gg1_w, const float* gg1_b, const float* ln_g, const float* ln_b,
    const float* gg2_w, const float* gg2_b, float* wg)
{
    __shared__ float guid[64][4];
    __shared__ float mu_s[64], rstd_s[64];
    __shared__ float Tk[16][69];
    __shared__ float Wt[16][65];
    const int tid = threadIdx.x;
    const int lane = tid & 63;
    const int wave = tid >> 6;
    const int row0 = blockIdx.x * 64;
    const int tr = (tid >> 4) * 4;
    const int tc = (tid & 15) * 4;

    if (tid < 192) guid[tid / 3][tid % 3] = guidance[(size_t)row0 * 3 + tid];
    __syncthreads();
    for (int i = 0; i < 16; i++) {
        int tok = wave * 16 + i;
        float g0 = guid[tok][0], g1 = guid[tok][1], g2 = guid[tok][2];
        float sum = 0.f, sumsq = 0.f;
#pragma unroll
        for (int j = 0; j < 8; j++) {
            int dim = j * 64 + lane;
            float t = gg1_w[dim*3]*g0 + gg1_w[dim*3+1]*g1 + gg1_w[dim*3+2]*g2 + gg1_b[dim];
            sum += t; sumsq += t * t;
        }
#pragma unroll
        for (int off = 32; off >= 1; off >>= 1) {
            sum += __shfl_xor(sum, off); sumsq += __shfl_xor(sumsq, off);
        }
        if (lane == 0) {
            float mu = sum * (1.f / 512.f);
            float var = fmaxf(sumsq * (1.f / 512.f) - mu * mu, 0.f);
            mu_s[tok] = mu;
            rstd_s[tok] = 1.f / sqrtf(var + 1e-5f);
        }
    }
    __syncthreads();

    for (int ct = 0; ct < 8; ct++) {
        float acc_g[4][4], acc_z[4][4];
#pragma unroll
        for (int i = 0; i < 4; i++)
#pragma unroll
            for (int j = 0; j < 4; j++) { acc_g[i][j] = 0.f; acc_z[i][j] = 0.f; }
        for (int k0 = 0; k0 < 512; k0 += 16) {
            __syncthreads();
            for (int i = tid; i < 16 * 64; i += 256) {
                int k = i >> 6, tok = i & 63;
                int dim = k0 + k;
                float t = gg1_w[dim*3]*guid[tok][0] + gg1_w[dim*3+1]*guid[tok][1]
                        + gg1_w[dim*3+2]*guid[tok][2] + gg1_b[dim];
                t = (t - mu_s[tok]) * rstd_s[tok] * ln_g[dim] + ln_b[dim];
                Tk[k][tok] = 0.5f * t * (1.f + erff(t * 0.70710678118654752440f));
            }
            for (int i = tid; i < 16 * 64; i += 256) {
                int n = i >> 4, k = i & 15;
                Wt[k][n] = gg2_w[(size_t)(1024 + 64 * ct + n) * 512 + k0 + k];
            }
            __syncthreads();
            float part[4][4];
#pragma unroll
            for (int i = 0; i < 4; i++)
#pragma unroll
                for (int j = 0; j < 4; j++) part[i][j] = 0.f;
#pragma unroll
            for (int kk = 0; kk < 16; kk++) {
                float a[4], b[4];
#pragma unroll
                for (int i = 0; i < 4; i++) a[i] = Tk[kk][tr + i];
#pragma unroll
                for (int j = 0; j < 4; j++) b[j] = Wt[kk][tc + j];
#pragma unroll
                for (int i = 0; i < 4; i++)
#pragma unroll
                    for (int j = 0; j < 4; j++) part[i][j] += a[i] * b[j];
            }
#pragma unroll
            for (int i = 0; i < 4; i++)
#pragma unroll
                for (int j = 0; j < 4; j++) acc_g[i][j] += part[i][j];
        }
        for (int k0 = 0; k0 < 256; k0 += 16) {
            __syncthreads();
            for (int i = tid; i < 16 * 64; i += 256) {
                int l = i >> 4, k = i & 15;
                Tk[k][l] = x[(size_t)(row0 + l) * 256 + k0 + k];
            }
            for (int i = tid; i < 16 * 64; i += 256) {
                int n = i >> 4, k = i & 15;
                Wt[k][n] = in_proj_w[(size_t)(512 + 64 * ct + n) * 256 + k0 + k];
            }
            __syncthreads();
            float part[4][4];
#pragma unroll
            for (int i = 0; i < 4; i++)
#pragma unroll
                for (int j = 0; j < 4; j++) part[i][j] = 0.f;
#pragma unroll
            for (int kk = 0; kk < 16; kk++) {
                float a[4], b[4];
#pragma unroll
                for (int i = 0; i < 4; i++) a[i] = Tk[kk][tr + i];
#pragma unroll
                for (int j = 0; j < 4; j++) b[j] = Wt[kk][tc + j];
#pragma unroll
                for (int i = 0; i < 4; i++)
#pragma unroll
                    for (int j = 0; j < 4; j++) part[i][j] += a[i] * b[j];
            }
#pragma unroll
            for (int i = 0; i < 4; i++)
#pragma unroll
                for (int j = 0; j < 4; j++) acc_z[i][j] += part[i][j];
        }
#pragma unroll
        for (int i = 0; i < 4; i++) {
            int r = row0 + tr + i;
#pragma unroll
            for (int j = 0; j < 4; j++) {
                int c = 64 * ct + tc + j;
                float z = acc_z[i][j];
                float gate = sigf(acc_g[i][j] + gg2_b[1024 + c]);
                wg[(size_t)r * 512 + c] = z * sigf(z) * gate;
            }
        }
        __syncthreads();
    }
}

// ---------------------------------------------------------------------------
// Generic fp32 NT GEMM: out = A(N,K) @ W(M,K).T   (EPI 0 plain, 2 softplus)
// ---------------------------------------------------------------------------
template <int BN, int EPI>
__global__ __launch_bounds__(256) void gemm_nt(
    const float* A, const float* W, const float* bias,
    float* out0, int K, int ldo, int colbase)
{
    constexpr int BM = 64, BK = 16, TM = 4, TN = BN / 16;
    __shared__ float As[BK][BM + 1];
    __shared__ float Ws[BK][BN + 1];
    const int tid = threadIdx.x;
    const int row0 = blockIdx.x * BM;
    const int col0 = colbase + blockIdx.y * BN;
    const int tr = (tid / 16) * TM;
    const int tc = (tid % 16) * TN;
    float acc[TM][TN];
#pragma unroll
    for (int i = 0; i < TM; i++)
#pragma unroll
        for (int j = 0; j < TN; j++) acc[i][j] = 0.f;

    for (int k0 = 0; k0 < K; k0 += BK) {
        __syncthreads();
        for (int i = tid; i < BM * BK; i += 256) {
            int m = i / BK, k = i % BK;
            As[k][m] = A[(size_t)(row0 + m) * K + k0 + k];
        }
        for (int i = tid; i < BN * BK; i += 256) {
            int n = i / BK, k = i % BK;
            Ws[k][n] = W[(size_t)(col0 + n) * K + k0 + k];
        }
        __syncthreads();
        float part[TM][TN];
#pragma unroll
        for (int i = 0; i < TM; i++)
#pragma unroll
            for (int j = 0; j < TN; j++) part[i][j] = 0.f;
#pragma unroll
        for (int kk = 0; kk < BK; kk++) {
            float a[TM], b[TN];
#pragma unroll
            for (int i = 0; i < TM; i++) a[i] = As[kk][tr + i];
#pragma unroll
            for (int j = 0; j < TN; j++) b[j] = Ws[kk][tc + j];
#pragma unroll
            for (int i = 0; i < TM; i++)
#pragma unroll
                for (int j = 0; j < TN; j++) part[i][j] += a[i] * b[j];
        }
#pragma unroll
        for (int i = 0; i < TM; i++)
#pragma unroll
            for (int j = 0; j < TN; j++) acc[i][j] += part[i][j];
    }
#pragma unroll
    for (int i = 0; i < TM; i++) {
        int r = row0 + tr + i;
#pragma unroll
        for (int j = 0; j < TN; j++) {
            int c = col0 + tc + j;
            float v = acc[i][j];
            if (EPI == 2) {
                float s = v + bias[c];
                out0[(size_t)r * ldo + (c - colbase)] =
                    fmaxf(s, 0.f) + log1pf(expf(-fabsf(s)));
            } else {
                out0[(size_t)r * ldo + (c - colbase)] = clampf(v);
            }
        }
    }
}

// ---------------------------------------------------------------------------
// Selective scan (per 128-channel quarter), 3-pass chunked.
// ---------------------------------------------------------------------------
__global__ __launch_bounds__(128) void scan_pass1(
    const float* delta_q, const float* u_full, const float* xdbl,
    const float* A_log, int dbase, float* h_end, float* Ssum)
{
    int c = blockIdx.x;       // chunk
    int dl = threadIdx.x;     // 0..127
    int d = dbase + dl;
    float As[16];
#pragma unroll
    for (int s = 0; s < 16; s++) As[s] = -expf(A_log[d * 16 + s]);
    float h[16];
#pragma unroll
    for (int s = 0; s < 16; s++) h[s] = 0.f;
    float S = 0.f;
    __shared__ float Bs[CHUNK][17];
    int tbase = c * CHUNK;
    for (int i = dl; i < CHUNK * 16; i += 128) {
        int r = i >> 4, s = i & 15;
        Bs[r][s] = xdbl[(size_t)(tbase + r) * 32 + s];
    }
    __syncthreads();
    for (int tl = 0; tl < CHUNK; tl++) {
        size_t t = (size_t)tbase + tl;
        float de = delta_q[t * QCH + dl];
        float uu = u_full[t * DI + d];
        float du = de * uu;
        S += de;
#pragma unroll
        for (int s = 0; s < 16; s++)
            h[s] = __expf(de * As[s]) * h[s] + du * Bs[tl][s];
    }
    size_t base = ((size_t)c * QCH + dl) * 16;
#pragma unroll
    for (int s = 0; s < 16; s++) h_end[base + s] = h[s];
    Ssum[(size_t)c * QCH + dl] = S;
}

__global__ void scan_pass2(const float* h_end, const float* Ssum,
                           const float* A_log, int dbase, float* initS)
{
    int idx = blockIdx.x * blockDim.x + threadIdx.x;   // 0..2047 = dl*16+s
    int dl = idx >> 4;
    float As = -expf(A_log[(dbase + dl) * 16 + (idx & 15)]);
    float carry = 0.f;
    for (int c = 0; c < NCHUNK; c++) {
        initS[(size_t)c * (QCH * 16) + idx] = carry;
        float P = __expf(As * Ssum[(size_t)c * QCH + dl]);
        carry = P * carry + h_end[(size_t)c * (QCH * 16) + idx];
    }
}

__global__ __launch_bounds__(128) void scan_pass3(
    const float* delta_q, const float* u_full, const float* xdbl,
    const float* A_log, int dbase, const float* initS, const float* Dp,
    float* wg_ymod)
{
    int c = blockIdx.x;
    int dl = threadIdx.x;
    int d = dbase + dl;
    float As[16];
#pragma unroll
    for (int s = 0; s < 16; s++) As[s] = -expf(A_log[d * 16 + s]);
    float h[16];
#pragma unroll
    for (int s = 0; s < 16; s++)
        h[s] = initS[((size_t)c * QCH + dl) * 16 + s];
    float Dd = Dp[d];
    __shared__ float Bs[CHUNK][17];
    __shared__ float Cs[CHUNK][17];
    int tbase = c * CHUNK;
    for (int i = dl; i < CHUNK * 16; i += 128) {
        int r = i >> 4, s = i & 15;
        Bs[r][s] = xdbl[(size_t)(tbase + r) * 32 + s];
        Cs[r][s] = xdbl[(size_t)(tbase + r) * 32 + 16 + s];
    }
    __syncthreads();
    for (int tl = 0; tl < CHUNK; tl++) {
        size_t t = (size_t)tbase + tl;
        float de = delta_q[t * QCH + dl];
        float uu = u_full[t * DI + d];
        float du = de * uu;
        float y = Dd * uu;
#pragma unroll
        for (int s = 0; s < 16; s++) {
            h[s] = __expf(de * As[s]) * h[s] + du * Bs[tl][s];
            y += h[s] * Cs[tl][s];
        }
        wg_ymod[t * DI + d] = y * wg_ymod[t * DI + d];   // y * w_gate, in place
    }
}

// ---------------------------------------------------------------------------
extern "C" void kernel_launch(void* const* d_in, const int* in_sizes, int n_in,
                              void* d_out, int out_size, void* d_ws, size_t ws_size,
                              hipStream_t stream)
{
    fprintf(stderr, "[kernel_launch] ws_size=%zu out_size=%d n_in=%d\n",
            ws_size, out_size, n_in);

    const float* x         = (const float*)d_in[0];
    const float* guidance  = (const float*)d_in[1];
    const float* in_proj_w = (const float*)d_in[2];
    const float* conv_w    = (const float*)d_in[3];
    const float* conv_b    = (const float*)d_in[4];
    const float* x_proj_w  = (const float*)d_in[5];
    const float* dt_proj_w = (const float*)d_in[6];
    const float* dt_proj_b = (const float*)d_in[7];
    const float* gg1_w     = (const float*)d_in[8];
    const float* gg1_b     = (const float*)d_in[9];
    const float* ln_g      = (const float*)d_in[10];
    const float* ln_b      = (const float*)d_in[11];
    const float* gg2_w     = (const float*)d_in[12];
    const float* gg2_b     = (const float*)d_in[13];
    const float* A_log     = (const float*)d_in[14];
    const float* Dp        = (const float*)d_in[15];
    const float* out_proj_w= (const float*)d_in[16];
    float* out = (float*)d_out;

    // ws: two N x 512 fp32 buffers = 256 MiB exactly.
    float* P1 = (float*)d_ws;                    // x_mod (scan u)
    float* P2 = P1 + (size_t)NTOK * DI;          // w_gate -> y_mod (in place)

    // d_out as pre-final scratch (48.25 MiB of 64; final GEMM overwrites all).
    float* ob      = (float*)d_out;
    float* delta_q = ob;                                  // N x 128   (32 MiB)
    float* xdbl    = ob + (size_t)NTOK * QCH;             // N x 32    (8 MiB)
    float* h_end   = ob + (size_t)NTOK * (QCH + 32);      // 512*128*16 (4 MiB)
    float* Ssum    = h_end + (size_t)NCHUNK * QCH * DS;   // 512*128   (0.25 MiB)
    float* initS   = Ssum + (size_t)NCHUNK * QCH;         // 4 MiB

    // 1-2. fused front end -> x_mod (P1), w_gate (P2)
    fused_xmod<<<NTOK / 64, 256, 0, stream>>>(
        x, in_proj_w, guidance, gg1_w, gg1_b, ln_g, ln_b, gg2_w, gg2_b,
        conv_w, conv_b, P1);
    fused_wgate<<<NTOK / 64, 256, 0, stream>>>(
        x, in_proj_w, guidance, gg1_w, gg1_b, ln_g, ln_b, gg2_w, gg2_b, P2);
    // 3. xdbl = x_mod @ x_proj_w.T  (B|C)
    gemm_nt<32, 0><<<dim3(NTOK / 64, 1), 256, 0, stream>>>(
        P1, x_proj_w, nullptr, xdbl, DI, 32, 0);
    // 4. per 128-channel quarter: delta GEMM + 3-pass scan (y_mod over P2)
    for (int q = 0; q < 4; q++) {
        int dbase = q * QCH;
        gemm_nt<64, 2><<<dim3(NTOK / 64, 2), 256, 0, stream>>>(
            P1, dt_proj_w, dt_proj_b, delta_q, DI, QCH, dbase);
        scan_pass1<<<NCHUNK, 128, 0, stream>>>(
            delta_q, P1, xdbl, A_log, dbase, h_end, Ssum);
        scan_pass2<<<(QCH * DS) / 256, 256, 0, stream>>>(
            h_end, Ssum, A_log, dbase, initS);
        scan_pass3<<<NCHUNK, 128, 0, stream>>>(
            delta_q, P1, xdbl, A_log, dbase, initS, Dp, P2);
    }
    // 5. out = y_mod @ out_proj_w.T  (overwrites all d_out scratch)
    gemm_nt<64, 0><<<dim3(NTOK / 64, DMODEL / 64), 256, 0, stream>>>(
        P2, out_proj_w, nullptr, out, DI, DMODEL, 0);
}

// Round 6
// 4499.933 us; speedup vs baseline: 1.7072x; 1.7072x over previous
//
#include <hip/hip_runtime.h>
#include <math.h>

#define NTOK 65536
#define DMODEL 256
#define DI 512
#define DS 16
#define CHUNK 128
#define NCHUNK (NTOK / CHUNK)   // 512
#define QCH 128                 // channels per scan quarter

__device__ __forceinline__ float sigf(float x) { return 1.0f / (1.0f + expf(-x)); }

// ---------------------------------------------------------------------------
// in_conv_kernel: per 64-token block
//   x_in = x @ in_proj_w[0:512].T   (+4 halo rows for conv)
//   P1   = silu(causal_conv(x_in))          (gate applied later)
//   z    = x @ in_proj_w[512:1024].T ; P2 = silu(z)
// 512 threads; tiles 64(+4) x 128, BK=32, float4 LDS reads.
// ---------------------------------------------------------------------------
__global__ __launch_bounds__(512) void in_conv_kernel(
    const float* x, const float* in_proj_w, const float* conv_w,
    const float* conv_b, float* P1, float* P2)
{
    __shared__ float As[32][72];    // [k][row: 0..3 halo, 4..67 main]
    __shared__ float Wt[32][132];
    __shared__ float xt[68][132];
    const int tid = threadIdx.x;
    const int row0 = blockIdx.x * 64;
    const int tr = (tid & 15) * 4;
    const int tc = (tid >> 4) * 4;
    const int hr = tid >> 7;        // 0..3
    const int hc = tid & 127;       // 0..127

    for (int ct = 0; ct < 8; ct++) {
        float acc[4][4];
#pragma unroll
        for (int i = 0; i < 4; i++)
#pragma unroll
            for (int j = 0; j < 4; j++) acc[i][j] = 0.f;
        float acch = 0.f;
        for (int k0 = 0; k0 < 256; k0 += 32) {
            __syncthreads();
            for (int i = tid; i < 68 * 32; i += 512) {
                int l = i >> 5, k = i & 31;
                int gr = row0 - 4 + l;
                As[k][l] = (gr >= 0) ? x[(size_t)gr * 256 + k0 + k] : 0.f;
            }
            {
                int n = tid >> 2, kq = (tid & 3) * 8;
                const float* wp = in_proj_w + (size_t)(ct * 128 + n) * 256 + k0 + kq;
                float4 w0 = *(const float4*)wp, w1 = *(const float4*)(wp + 4);
                Wt[kq + 0][n] = w0.x; Wt[kq + 1][n] = w0.y;
                Wt[kq + 2][n] = w0.z; Wt[kq + 3][n] = w0.w;
                Wt[kq + 4][n] = w1.x; Wt[kq + 5][n] = w1.y;
                Wt[kq + 6][n] = w1.z; Wt[kq + 7][n] = w1.w;
            }
            __syncthreads();
#pragma unroll 8
            for (int kk = 0; kk < 32; kk++) {
                float4 a = *(const float4*)&As[kk][4 + tr];
                float4 b = *(const float4*)&Wt[kk][tc];
                acc[0][0] += a.x*b.x; acc[0][1] += a.x*b.y; acc[0][2] += a.x*b.z; acc[0][3] += a.x*b.w;
                acc[1][0] += a.y*b.x; acc[1][1] += a.y*b.y; acc[1][2] += a.y*b.z; acc[1][3] += a.y*b.w;
                acc[2][0] += a.z*b.x; acc[2][1] += a.z*b.y; acc[2][2] += a.z*b.z; acc[2][3] += a.z*b.w;
                acc[3][0] += a.w*b.x; acc[3][1] += a.w*b.y; acc[3][2] += a.w*b.z; acc[3][3] += a.w*b.w;
                if (ct < 4) acch += As[kk][hr] * Wt[kk][hc];
            }
        }
        if (ct < 4) {
            __syncthreads();
#pragma unroll
            for (int i = 0; i < 4; i++)
#pragma unroll
                for (int j = 0; j < 4; j++)
                    xt[4 + tr + i][tc + j] = acc[i][j];
            xt[hr][hc] = acch;
            __syncthreads();
#pragma unroll
            for (int i = 0; i < 4; i++) {
                int r = row0 + tr + i;
#pragma unroll
                for (int j = 0; j < 4; j++) {
                    int c = ct * 128 + tc + j;
                    float cv = conv_b[c];
#pragma unroll
                    for (int k = 0; k < 4; k++)
                        cv += conv_w[c * 4 + k] * xt[tr + i + 1 + k][tc + j];
                    P1[(size_t)r * 512 + c] = cv * sigf(cv);
                }
            }
        } else {
#pragma unroll
            for (int i = 0; i < 4; i++) {
                int r = row0 + tr + i;
                float4 zv;
                zv.x = acc[i][0]; zv.y = acc[i][1]; zv.z = acc[i][2]; zv.w = acc[i][3];
                zv.x = zv.x * sigf(zv.x); zv.y = zv.y * sigf(zv.y);
                zv.z = zv.z * sigf(zv.z); zv.w = zv.w * sigf(zv.w);
                *(float4*)&P2[(size_t)r * 512 + (ct - 4) * 128 + tc] = zv;
            }
        }
    }
}

// ---------------------------------------------------------------------------
// gates_kernel: per 64-token block
//   g = gelu(LN(guidance @ gg1_w.T + gg1_b))   computed ONCE into registers
//   P1 *= sigmoid(g @ gg2_w[0:512].T    + gg2_b[0:512])      (gate_in)
//   P2 *= sigmoid(g @ gg2_w[1024:1536].T + gg2_b[1024:1536]) (gate_out)
// Thread t holds g[token t&63][dims (t>>6)+8j], j=0..63 (64 VGPRs).
// ---------------------------------------------------------------------------
__global__ __launch_bounds__(512) void gates_kernel(
    const float* guidance, const float* gg1_w, const float* gg1_b,
    const float* ln_g, const float* ln_b,
    const float* gg2_w, const float* gg2_b,
    float* P1, float* P2)
{
    __shared__ float gs[128][68];   // 128-k slice of g, [k][token]
    __shared__ float Wt[32][132];
    __shared__ float red_s[64][9], red_q[64][9];
    const int tid = threadIdx.x;
    const int tok = tid & 63;
    const int o = tid >> 6;          // 0..7
    const int row0 = blockIdx.x * 64;
    const int tr = (tid & 15) * 4;
    const int tc = (tid >> 4) * 4;

    // ---- Phase A: g into registers ----
    float g0 = guidance[(size_t)(row0 + tok) * 3 + 0];
    float g1 = guidance[(size_t)(row0 + tok) * 3 + 1];
    float g2 = guidance[(size_t)(row0 + tok) * 3 + 2];
    float v[64];
    float sum = 0.f, sumsq = 0.f;
#pragma unroll
    for (int j = 0; j < 64; j++) {
        int d = o + 8 * j;
        float t = gg1_w[d * 3 + 0] * g0 + gg1_w[d * 3 + 1] * g1 +
                  gg1_w[d * 3 + 2] * g2 + gg1_b[d];
        v[j] = t;
        sum += t; sumsq += t * t;
    }
    red_s[tok][o] = sum; red_q[tok][o] = sumsq;
    __syncthreads();
    sum = 0.f; sumsq = 0.f;
#pragma unroll
    for (int oo = 0; oo < 8; oo++) { sum += red_s[tok][oo]; sumsq += red_q[tok][oo]; }
    float mu = sum * (1.f / 512.f);
    float var = fmaxf(sumsq * (1.f / 512.f) - mu * mu, 0.f);
    float rstd = 1.f / sqrtf(var + 1e-5f);
#pragma unroll
    for (int j = 0; j < 64; j++) {
        int d = o + 8 * j;
        float t = (v[j] - mu) * rstd * ln_g[d] + ln_b[d];
        v[j] = 0.5f * t * (1.f + erff(t * 0.70710678118654752440f));
    }

    // ---- Phase B: two gate GEMMs, 4 col-tiles of 128 each ----
    for (int gm = 0; gm < 2; gm++) {
        const float* Wrow = gg2_w + (size_t)(gm ? 1024 : 0) * 512;
        const float* bias = gg2_b + (gm ? 1024 : 0);
        float* P = gm ? P2 : P1;
        for (int ct = 0; ct < 4; ct++) {
            float acc[4][4];
#pragma unroll
            for (int i = 0; i < 4; i++)
#pragma unroll
                for (int j = 0; j < 4; j++) acc[i][j] = 0.f;
#pragma unroll
            for (int k0c = 0; k0c < 512; k0c += 128) {
                const int jb = k0c >> 3;
#pragma unroll
                for (int sub = 0; sub < 4; sub++) {
                    __syncthreads();
                    if (sub == 0) {
#pragma unroll
                        for (int m = 0; m < 16; m++)
                            gs[o + 8 * m][tok] = v[jb + m];
                    }
                    {
                        int k0 = k0c + sub * 32;
                        int n = tid >> 2, kq = (tid & 3) * 8;
                        const float* wp = Wrow + (size_t)(ct * 128 + n) * 512 + k0 + kq;
                        float4 w0 = *(const float4*)wp, w1 = *(const float4*)(wp + 4);
                        Wt[kq + 0][n] = w0.x; Wt[kq + 1][n] = w0.y;
                        Wt[kq + 2][n] = w0.z; Wt[kq + 3][n] = w0.w;
                        Wt[kq + 4][n] = w1.x; Wt[kq + 5][n] = w1.y;
                        Wt[kq + 6][n] = w1.z; Wt[kq + 7][n] = w1.w;
                    }
                    __syncthreads();
#pragma unroll 8
                    for (int kk = 0; kk < 32; kk++) {
                        float4 a = *(const float4*)&gs[sub * 32 + kk][tr];
                        float4 b = *(const float4*)&Wt[kk][tc];
                        acc[0][0] += a.x*b.x; acc[0][1] += a.x*b.y; acc[0][2] += a.x*b.z; acc[0][3] += a.x*b.w;
                        acc[1][0] += a.y*b.x; acc[1][1] += a.y*b.y; acc[1][2] += a.y*b.z; acc[1][3] += a.y*b.w;
                        acc[2][0] += a.z*b.x; acc[2][1] += a.z*b.y; acc[2][2] += a.z*b.z; acc[2][3] += a.z*b.w;
                        acc[3][0] += a.w*b.x; acc[3][1] += a.w*b.y; acc[3][2] += a.w*b.z; acc[3][3] += a.w*b.w;
                    }
                }
            }
#pragma unroll
            for (int i = 0; i < 4; i++) {
                int r = row0 + tr + i;
                size_t base = (size_t)r * 512 + ct * 128 + tc;
                float4 pv = *(float4*)&P[base];
                pv.x *= sigf(acc[i][0] + bias[ct * 128 + tc + 0]);
                pv.y *= sigf(acc[i][1] + bias[ct * 128 + tc + 1]);
                pv.z *= sigf(acc[i][2] + bias[ct * 128 + tc + 2]);
                pv.w *= sigf(acc[i][3] + bias[ct * 128 + tc + 3]);
                *(float4*)&P[base] = pv;
            }
        }
    }
}

// ---------------------------------------------------------------------------
// gemm512: out = A(N,K) @ W(M,K).T, 64x128 tile, 512 threads, float4 reads.
// EPI 0: plain store   EPI 2: softplus(v + bias[c])
// ---------------------------------------------------------------------------
template <int EPI>
__global__ __launch_bounds__(512) void gemm512(
    const float* A, const float* W, const float* bias,
    float* out0, int K, int ldo, int colbase)
{
    __shared__ float As[32][68];
    __shared__ float Wt[32][132];
    const int tid = threadIdx.x;
    const int row0 = blockIdx.x * 64;
    const int col0 = colbase + blockIdx.y * 128;
    const int tr = (tid & 15) * 4;
    const int tc = (tid >> 4) * 4;
    float acc[4][4];
#pragma unroll
    for (int i = 0; i < 4; i++)
#pragma unroll
        for (int j = 0; j < 4; j++) acc[i][j] = 0.f;

    for (int k0 = 0; k0 < K; k0 += 32) {
        __syncthreads();
        for (int i = tid; i < 64 * 32; i += 512) {
            int l = i >> 5, k = i & 31;
            As[k][l] = A[(size_t)(row0 + l) * K + k0 + k];
        }
        {
            int n = tid >> 2, kq = (tid & 3) * 8;
            const float* wp = W + (size_t)(col0 + n) * K + k0 + kq;
            float4 w0 = *(const float4*)wp, w1 = *(const float4*)(wp + 4);
            Wt[kq + 0][n] = w0.x; Wt[kq + 1][n] = w0.y;
            Wt[kq + 2][n] = w0.z; Wt[kq + 3][n] = w0.w;
            Wt[kq + 4][n] = w1.x; Wt[kq + 5][n] = w1.y;
            Wt[kq + 6][n] = w1.z; Wt[kq + 7][n] = w1.w;
        }
        __syncthreads();
#pragma unroll 8
        for (int kk = 0; kk < 32; kk++) {
            float4 a = *(const float4*)&As[kk][tr];
            float4 b = *(const float4*)&Wt[kk][tc];
            acc[0][0] += a.x*b.x; acc[0][1] += a.x*b.y; acc[0][2] += a.x*b.z; acc[0][3] += a.x*b.w;
            acc[1][0] += a.y*b.x; acc[1][1] += a.y*b.y; acc[1][2] += a.y*b.z; acc[1][3] += a.y*b.w;
            acc[2][0] += a.z*b.x; acc[2][1] += a.z*b.y; acc[2][2] += a.z*b.z; acc[2][3] += a.z*b.w;
            acc[3][0] += a.w*b.x; acc[3][1] += a.w*b.y; acc[3][2] += a.w*b.z; acc[3][3] += a.w*b.w;
        }
    }
#pragma unroll
    for (int i = 0; i < 4; i++) {
        int r = row0 + tr + i;
#pragma unroll
        for (int j = 0; j < 4; j++) {
            int c = col0 + tc + j;
            float vv = acc[i][j];
            if (EPI == 2) {
                float s = vv + bias[c];
                out0[(size_t)r * ldo + (c - colbase)] =
                    fmaxf(s, 0.f) + log1pf(expf(-fabsf(s)));
            } else {
                out0[(size_t)r * ldo + (c - colbase)] = vv;
            }
        }
    }
}

// ---------------------------------------------------------------------------
// Small GEMM for x_proj (32 cols), 256 threads (round-5 structure).
// ---------------------------------------------------------------------------
__global__ __launch_bounds__(256) void gemm_nt32(
    const float* A, const float* W, float* out0, int K, int ldo)
{
    __shared__ float As[16][65];
    __shared__ float Ws[16][33];
    const int tid = threadIdx.x;
    const int row0 = blockIdx.x * 64;
    const int tr = (tid / 16) * 4;
    const int tc = (tid % 16) * 2;
    float acc[4][2];
#pragma unroll
    for (int i = 0; i < 4; i++) { acc[i][0] = 0.f; acc[i][1] = 0.f; }
    for (int k0 = 0; k0 < K; k0 += 16) {
        __syncthreads();
        for (int i = tid; i < 64 * 16; i += 256) {
            int m = i / 16, k = i % 16;
            As[k][m] = A[(size_t)(row0 + m) * K + k0 + k];
        }
        for (int i = tid; i < 32 * 16; i += 256) {
            int n = i / 16, k = i % 16;
            Ws[k][n] = W[(size_t)n * K + k0 + k];
        }
        __syncthreads();
#pragma unroll
        for (int kk = 0; kk < 16; kk++) {
            float a[4], b[2];
#pragma unroll
            for (int i = 0; i < 4; i++) a[i] = As[kk][tr + i];
            b[0] = Ws[kk][tc]; b[1] = Ws[kk][tc + 1];
#pragma unroll
            for (int i = 0; i < 4; i++) { acc[i][0] += a[i] * b[0]; acc[i][1] += a[i] * b[1]; }
        }
    }
#pragma unroll
    for (int i = 0; i < 4; i++) {
        int r = row0 + tr + i;
        out0[(size_t)r * ldo + tc] = acc[i][0];
        out0[(size_t)r * ldo + tc + 1] = acc[i][1];
    }
}

// ---------------------------------------------------------------------------
// Selective scan (per 128-channel quarter), 3-pass chunked. (round-5, passed)
// ---------------------------------------------------------------------------
__global__ __launch_bounds__(128) void scan_pass1(
    const float* delta_q, const float* u_full, const float* xdbl,
    const float* A_log, int dbase, float* h_end, float* Ssum)
{
    int c = blockIdx.x;
    int dl = threadIdx.x;
    int d = dbase + dl;
    float As[16];
#pragma unroll
    for (int s = 0; s < 16; s++) As[s] = -expf(A_log[d * 16 + s]);
    float h[16];
#pragma unroll
    for (int s = 0; s < 16; s++) h[s] = 0.f;
    float S = 0.f;
    __shared__ float Bs[CHUNK][17];
    int tbase = c * CHUNK;
    for (int i = dl; i < CHUNK * 16; i += 128) {
        int r = i >> 4, s = i & 15;
        Bs[r][s] = xdbl[(size_t)(tbase + r) * 32 + s];
    }
    __syncthreads();
    for (int tl = 0; tl < CHUNK; tl++) {
        size_t t = (size_t)tbase + tl;
        float de = delta_q[t * QCH + dl];
        float uu = u_full[t * DI + d];
        float du = de * uu;
        S += de;
#pragma unroll
        for (int s = 0; s < 16; s++)
            h[s] = __expf(de * As[s]) * h[s] + du * Bs[tl][s];
    }
    size_t base = ((size_t)c * QCH + dl) * 16;
#pragma unroll
    for (int s = 0; s < 16; s++) h_end[base + s] = h[s];
    Ssum[(size_t)c * QCH + dl] = S;
}

__global__ void scan_pass2(const float* h_end, const float* Ssum,
                           const float* A_log, int dbase, float* initS)
{
    int idx = blockIdx.x * blockDim.x + threadIdx.x;   // 0..2047 = dl*16+s
    int dl = idx >> 4;
    float As = -expf(A_log[(dbase + dl) * 16 + (idx & 15)]);
    float carry = 0.f;
    for (int c = 0; c < NCHUNK; c++) {
        initS[(size_t)c * (QCH * 16) + idx] = carry;
        float P = __expf(As * Ssum[(size_t)c * QCH + dl]);
        carry = P * carry + h_end[(size_t)c * (QCH * 16) + idx];
    }
}

__global__ __launch_bounds__(128) void scan_pass3(
    const float* delta_q, const float* u_full, const float* xdbl,
    const float* A_log, int dbase, const float* initS, const float* Dp,
    float* wg_ymod)
{
    int c = blockIdx.x;
    int dl = threadIdx.x;
    int d = dbase + dl;
    float As[16];
#pragma unroll
    for (int s = 0; s < 16; s++) As[s] = -expf(A_log[d * 16 + s]);
    float h[16];
#pragma unroll
    for (int s = 0; s < 16; s++)
        h[s] = initS[((size_t)c * QCH + dl) * 16 + s];
    float Dd = Dp[d];
    __shared__ float Bs[CHUNK][17];
    __shared__ float Cs[CHUNK][17];
    int tbase = c * CHUNK;
    for (int i = dl; i < CHUNK * 16; i += 128) {
        int r = i >> 4, s = i & 15;
        Bs[r][s] = xdbl[(size_t)(tbase + r) * 32 + s];
        Cs[r][s] = xdbl[(size_t)(tbase + r) * 32 + 16 + s];
    }
    __syncthreads();
    for (int tl = 0; tl < CHUNK; tl++) {
        size_t t = (size_t)tbase + tl;
        float de = delta_q[t * QCH + dl];
        float uu = u_full[t * DI + d];
        float du = de * uu;
        float y = Dd * uu;
#pragma unroll
        for (int s = 0; s < 16; s++) {
            h[s] = __expf(de * As[s]) * h[s] + du * Bs[tl][s];
            y += h[s] * Cs[tl][s];
        }
        wg_ymod[t * DI + d] = y * wg_ymod[t * DI + d];   // y * w_gate, in place
    }
}

// ---------------------------------------------------------------------------
extern "C" void kernel_launch(void* const* d_in, const int* in_sizes, int n_in,
                              void* d_out, int out_size, void* d_ws, size_t ws_size,
                              hipStream_t stream)
{
    const float* x         = (const float*)d_in[0];
    const float* guidance  = (const float*)d_in[1];
    const float* in_proj_w = (const float*)d_in[2];
    const float* conv_w    = (const float*)d_in[3];
    const float* conv_b    = (const float*)d_in[4];
    const float* x_proj_w  = (const float*)d_in[5];
    const float* dt_proj_w = (const float*)d_in[6];
    const float* dt_proj_b = (const float*)d_in[7];
    const float* gg1_w     = (const float*)d_in[8];
    const float* gg1_b     = (const float*)d_in[9];
    const float* ln_g      = (const float*)d_in[10];
    const float* ln_b      = (const float*)d_in[11];
    const float* gg2_w     = (const float*)d_in[12];
    const float* gg2_b     = (const float*)d_in[13];
    const float* A_log     = (const float*)d_in[14];
    const float* Dp        = (const float*)d_in[15];
    const float* out_proj_w= (const float*)d_in[16];
    float* out = (float*)d_out;

    // ws: two N x 512 fp32 buffers = 256 MiB exactly.
    float* P1 = (float*)d_ws;                    // x_mod (scan u)
    float* P2 = P1 + (size_t)NTOK * DI;          // w_gate -> y_mod (in place)

    // d_out as pre-final scratch (48.25 MiB of 64; final GEMM overwrites all).
    float* ob      = (float*)d_out;
    float* delta_q = ob;                                  // N x 128   (32 MiB)
    float* xdbl    = ob + (size_t)NTOK * QCH;             // N x 32    (8 MiB)
    float* h_end   = ob + (size_t)NTOK * (QCH + 32);      // 4 MiB
    float* Ssum    = h_end + (size_t)NCHUNK * QCH * DS;   // 0.25 MiB
    float* initS   = Ssum + (size_t)NCHUNK * QCH;         // 4 MiB

    // 1. in_proj + conv + silu -> P1 = silu(conv(x_in)), P2 = silu(z)
    in_conv_kernel<<<NTOK / 64, 512, 0, stream>>>(
        x, in_proj_w, conv_w, conv_b, P1, P2);
    // 2. gates: P1 *= gate_in, P2 *= gate_out
    gates_kernel<<<NTOK / 64, 512, 0, stream>>>(
        guidance, gg1_w, gg1_b, ln_g, ln_b, gg2_w, gg2_b, P1, P2);
    // 3. xdbl = x_mod @ x_proj_w.T  (B|C)
    gemm_nt32<<<NTOK / 64, 256, 0, stream>>>(P1, x_proj_w, xdbl, DI, 32);
    // 4. per 128-channel quarter: delta GEMM + 3-pass scan (y_mod over P2)
    for (int q = 0; q < 4; q++) {
        int dbase = q * QCH;
        gemm512<2><<<dim3(NTOK / 64, 1), 512, 0, stream>>>(
            P1, dt_proj_w, dt_proj_b, delta_q, DI, QCH, dbase);
        scan_pass1<<<NCHUNK, 128, 0, stream>>>(
            delta_q, P1, xdbl, A_log, dbase, h_end, Ssum);
        scan_pass2<<<(QCH * DS) / 256, 256, 0, stream>>>(
            h_end, Ssum, A_log, dbase, initS);
        scan_pass3<<<NCHUNK, 128, 0, stream>>>(
            delta_q, P1, xdbl, A_log, dbase, initS, Dp, P2);
    }
    // 5. out = y_mod @ out_proj_w.T  (overwrites all d_out scratch)
    gemm512<0><<<dim3(NTOK / 64, 2), 512, 0, stream>>>(
        P2, out_proj_w, nullptr, out, DI, DMODEL, 0);
}